// Round 6
// baseline (1455.335 us; speedup 1.0000x reference)
//
#include <hip/hip_runtime.h>
#include <hip/hip_bf16.h>
#include <math.h>

#define N_BATCH 2048
#define T_STEPS 50
#define NCODES  40
#define MH      526
#define AUXD    10
#define WLROWS  536    // MH + AUXD
#define KPAD    544    // WLROWS padded to 17*32
#define E_DIM   256
#define G_DIM   1024   // 4*E
#define BMR     32     // batch rows per recurrence block (2 row-groups)
#define TCHUNK  10     // time steps per chunk (5 chunks)
#define MBLK    32     // (n,t) rows per fused block

typedef __attribute__((ext_vector_type(8))) short short8;   // 8 bf16 = 4 VGPR
typedef __attribute__((ext_vector_type(4))) short short4v;  // 4 bf16 = 2 VGPR
typedef __attribute__((ext_vector_type(4))) float f32x4;

__device__ __forceinline__ short f2bf(float f) {
    __hip_bfloat16 h = __float2bfloat16(f);
    return *reinterpret_cast<short*>(&h);
}
__device__ __forceinline__ float bf2f(unsigned short u) {
    return __uint_as_float(((unsigned int)u) << 16);
}
__device__ __forceinline__ float sigf(float x) {
    return 1.f / (1.f + __expf(-x));
}
__device__ __forceinline__ float tanhfast(float x) {
    return 2.f / (1.f + __expf(-2.f * x)) - 1.f;
}

// ---------------------------------------------------------------------------
// Prep A: Wlt[n][k] bf16 = W_lin[k][n] (k<536, zero-padded to 544)
// ---------------------------------------------------------------------------
__global__ __launch_bounds__(256) void k_prepwl(
    const float* __restrict__ W_lin, short* __restrict__ Wlt)
{
    const int tid = threadIdx.x;
    const int kt = blockIdx.x >> 2;      // 0..16
    const int nt = blockIdx.x & 3;       // 0..3
    const int k0 = kt * 32, n0 = nt * 64;

    __shared__ float tile[32][65];

    #pragma unroll
    for (int it = 0; it < 8; ++it) {
        const int idx = tid + it * 256;
        const int kk = idx >> 6, nn = idx & 63;
        const int k = k0 + kk;
        tile[kk][nn] = (k < WLROWS) ? W_lin[(size_t)k * E_DIM + n0 + nn] : 0.f;
    }
    __syncthreads();

    const int n  = tid >> 2;
    const int kg = tid & 3;
    int4 v;
    int* vi = (int*)&v;
    #pragma unroll
    for (int j = 0; j < 4; ++j) {
        int lo = f2bf(tile[kg * 8 + 2 * j][n]) & 0xffff;
        int hi = f2bf(tile[kg * 8 + 2 * j + 1][n]) & 0xffff;
        vi[j] = lo | (hi << 16);
    }
    *(int4*)(Wlt + (size_t)(n0 + n) * KPAD + k0 + kg * 8) = v;
}

// ---------------------------------------------------------------------------
// Prep B: Wt[n][k] (bf16, k=0..511) = [K;R][k][n]
// ---------------------------------------------------------------------------
__global__ __launch_bounds__(256) void k_prep(
    const float* __restrict__ K, const float* __restrict__ R,
    short* __restrict__ Wt)
{
    const int tid = threadIdx.x;
    const int kt = blockIdx.x & 7;
    const int nt = blockIdx.x >> 3;
    const int k0 = kt * 64, n0 = nt * 64;

    __shared__ float tile[64][65];

    const int nloc_r = tid & 63;
    for (int kloc = tid >> 6; kloc < 64; kloc += 4) {
        const int k = k0 + kloc;
        float v = (k < 256) ? K[(size_t)k * G_DIM + n0 + nloc_r]
                            : R[(size_t)(k - 256) * G_DIM + n0 + nloc_r];
        tile[kloc][nloc_r] = v;
    }
    __syncthreads();

    const int nloc = tid >> 2;
    const int kc   = (tid & 3) * 16;
    int* dst = (int*)(Wt + (size_t)(n0 + nloc) * 512 + k0 + kc);
    #pragma unroll
    for (int j = 0; j < 8; ++j) {
        int lo = f2bf(tile[kc + 2 * j][nloc]) & 0xffff;
        int hi = f2bf(tile[kc + 2 * j + 1][nloc]) & 0xffff;
        dst[j] = lo | (hi << 16);
    }
}

// ---------------------------------------------------------------------------
// Fused embed + xz GEMM, tl-major. Block = 32 consecutive n at fixed tl.
// Output in k_rec fragment order: frag idx = ((rgg*TCHUNK+tl)*16 + wc)*4 + f,
// 256 shorts each, lane writes short4 at +lane*4.
// Producer (w,cb) -> consumer (wc,f): wc=(w&1)*8+cb, f=w>>1.
// ---------------------------------------------------------------------------
__global__ __launch_bounds__(512) void k_fused(
    const int* __restrict__ code, const float* __restrict__ aux,
    const short* __restrict__ Wlt, const float* __restrict__ b_lin,
    const short* __restrict__ Wt, short* __restrict__ xzp, int t0)
{
    const int tid  = threadIdx.x;
    const int w    = tid >> 6;
    const int lane = tid & 63;
    const int lr   = lane & 15;
    const int p    = lane >> 4;
    const int tl   = blockIdx.x >> 6;          // 0..TCHUNK-1
    const int ng   = blockIdx.x & 63;
    const int n0   = ng * MBLK;                // 32 consecutive batch rows
    const int t    = t0 + tl;

    __shared__ __align__(16) short oh[MBLK][552];
    __shared__ __align__(16) short xs[MBLK][264];

    // ---- zero one-hot ----
    for (int i = tid; i < (MBLK * 552) / 8; i += 512)
        ((int4*)&oh[0][0])[i] = (int4){0, 0, 0, 0};
    __syncthreads();

    // ---- scatter codes (presence; duplicates idempotent; drop c==0) ----
    for (int i = tid; i < MBLK * NCODES; i += 512) {
        const int r = i / NCODES;
        const int j = i - r * NCODES;
        const int c = code[((size_t)(n0 + r) * T_STEPS + t) * NCODES + j];
        if (c > 0) ((unsigned short*)&oh[0][0])[r * 552 + (c - 1)] = 0x3F80;
    }
    if (tid < MBLK * AUXD) {
        const int r = tid / AUXD;
        const int a = tid - r * AUXD;
        oh[r][MH + a] = f2bf(aux[((size_t)(n0 + r) * T_STEPS + t) * AUXD + a]);
    }
    __syncthreads();

    // ---- Phase 2: xs = relu(oh @ Wlt^T + b_lin), wave cols w*32.. ----
    {
        f32x4 acc[2][2];
        #pragma unroll
        for (int rb = 0; rb < 2; ++rb)
            #pragma unroll
            for (int cb = 0; cb < 2; ++cb)
                acc[rb][cb] = (f32x4){0.f, 0.f, 0.f, 0.f};

        for (int kk = 0; kk < 17; ++kk) {
            short8 a0 = *(const short8*)&oh[lr][kk * 32 + p * 8];
            short8 a1 = *(const short8*)&oh[16 + lr][kk * 32 + p * 8];
            #pragma unroll
            for (int cb = 0; cb < 2; ++cb) {
                short8 bf = *(const short8*)(Wlt +
                    (size_t)(w * 32 + cb * 16 + lr) * KPAD + kk * 32 + p * 8);
                acc[0][cb] = __builtin_amdgcn_mfma_f32_16x16x32_bf16(a0, bf, acc[0][cb], 0, 0, 0);
                acc[1][cb] = __builtin_amdgcn_mfma_f32_16x16x32_bf16(a1, bf, acc[1][cb], 0, 0, 0);
            }
        }
        float bias[2];
        #pragma unroll
        for (int cb = 0; cb < 2; ++cb) bias[cb] = b_lin[w * 32 + cb * 16 + lr];
        __syncthreads();
        #pragma unroll
        for (int rb = 0; rb < 2; ++rb)
            #pragma unroll
            for (int cb = 0; cb < 2; ++cb)
                #pragma unroll
                for (int rr = 0; rr < 4; ++rr)
                    xs[rb * 16 + p * 4 + rr][w * 32 + cb * 16 + lr] =
                        f2bf(fmaxf(acc[rb][cb][rr] + bias[cb], 0.f));
        __syncthreads();
    }

    // ---- Phase 3: xz = xs @ Wt_K^T, frag-order output ----
    {
        f32x4 acc[2][8];
        #pragma unroll
        for (int rb = 0; rb < 2; ++rb)
            #pragma unroll
            for (int cb = 0; cb < 8; ++cb)
                acc[rb][cb] = (f32x4){0.f, 0.f, 0.f, 0.f};

        for (int kb = 0; kb < 8; ++kb) {
            short8 a0 = *(const short8*)&xs[lr][kb * 32 + p * 8];
            short8 a1 = *(const short8*)&xs[16 + lr][kb * 32 + p * 8];
            short8 bf[8];
            #pragma unroll
            for (int cb = 0; cb < 8; ++cb)
                bf[cb] = *(const short8*)(Wt +
                    (size_t)(w * 128 + cb * 16 + lr) * 512 + kb * 32 + p * 8);
            #pragma unroll
            for (int cb = 0; cb < 8; ++cb) {
                acc[0][cb] = __builtin_amdgcn_mfma_f32_16x16x32_bf16(a0, bf[cb], acc[0][cb], 0, 0, 0);
                acc[1][cb] = __builtin_amdgcn_mfma_f32_16x16x32_bf16(a1, bf[cb], acc[1][cb], 0, 0, 0);
            }
        }
        #pragma unroll
        for (int rb = 0; rb < 2; ++rb) {
            const int rgg = ng * 2 + rb;     // global 16-row group
            #pragma unroll
            for (int cb = 0; cb < 8; ++cb) {
                const int wc = (w & 1) * 8 + cb;
                const int f  = w >> 1;
                short4v v;
                #pragma unroll
                for (int rr = 0; rr < 4; ++rr) v[rr] = f2bf(acc[rb][cb][rr]);
                *(short4v*)(xzp +
                    ((((size_t)rgg * TCHUNK + tl) * 16 + wc) * 4 + f) * 256 +
                    lane * 4) = v;
            }
        }
    }
}

// ---------------------------------------------------------------------------
// Recurrence v3: 64 blocks x 1024 thr (16 waves). Block owns 32 rows
// (2 row-groups). Wave wc owns e-cols wc*16..+15, ALL 4 gates (f=0..3 at
// col f*256+e) -> gates in-reg, no partial exchange. Each B-frag feeds 2
// MFMAs (2 row-groups). h in frag-major double-buffered LDS (conflict-free
// ds_read_b128, 1 barrier/step). xz acc-init coalesced + prefetched.
// ---------------------------------------------------------------------------
__global__ __launch_bounds__(1024, 4) void k_rec(
    const short* __restrict__ xzp, const int* __restrict__ length,
    const short* __restrict__ Wt, const float* __restrict__ b,
    short* __restrict__ h_state, float* __restrict__ c_state,
    float* __restrict__ xlast, int t0)
{
    const int tid  = threadIdx.x;
    const int wc   = tid >> 6;           // 0..15
    const int lane = tid & 63;
    const int lr   = lane & 15;
    const int p    = lane >> 4;
    const int r0   = blockIdx.x * BMR;

    __shared__ __align__(16) short h_f[2][2][8][512]; // [buf][rg][kk][lane*8+j]
    __shared__ int s_len[BMR];
    __shared__ int s_maxlen;

    if (tid < BMR) s_len[tid] = length[r0 + tid];
    __syncthreads();
    if (tid == 0) {
        int m = 0;
        for (int r2 = 0; r2 < BMR; ++r2) m = max(m, s_len[r2]);
        s_maxlen = m;
    }
    __syncthreads();
    const int mlen = s_maxlen;
    if (mlen <= t0) return;
    const int steps = min(TCHUNK, mlen - t0);

    const int e   = wc * 16 + lr;        // this thread's e-column
    const int kkw = e >> 5;              // h_f write slot
    const int law = ((e >> 3) & 3) * 16; // pa*16
    const int jw  = e & 7;

    float bias[4];
    #pragma unroll
    for (int g = 0; g < 4; ++g) bias[g] = b[g * 256 + e];

    int len_r[2][4];
    #pragma unroll
    for (int rg = 0; rg < 2; ++rg)
        #pragma unroll
        for (int rr = 0; rr < 4; ++rr)
            len_r[rg][rr] = s_len[rg * 16 + p * 4 + rr];

    // Wt row bases (R-half), t-invariant
    const short* wrow[4];
    #pragma unroll
    for (int f = 0; f < 4; ++f)
        wrow[f] = Wt + (size_t)(f * 256 + e) * 512 + 256 + p * 8;

    float creg[2][4];
    if (t0 == 0) {
        for (int i = tid; i < 2 * 2 * 8 * 512 / 2; i += 1024)
            ((int*)&h_f[0][0][0][0])[i] = 0;
        #pragma unroll
        for (int rg = 0; rg < 2; ++rg)
            #pragma unroll
            for (int rr = 0; rr < 4; ++rr) creg[rg][rr] = 0.f;
    } else {
        #pragma unroll
        for (int rg = 0; rg < 2; ++rg)
            #pragma unroll
            for (int rr = 0; rr < 4; ++rr) {
                const int row = r0 + rg * 16 + p * 4 + rr;
                creg[rg][rr] = c_state[(size_t)row * E_DIM + e];
                h_f[0][rg][kkw][(law + p * 4 + rr) * 8 + jw] =
                    h_state[(size_t)row * E_DIM + e];
            }
    }
    __syncthreads();

    const int rgg0 = (r0 >> 4);

    // prefetch xz for tl=0
    short4v xv[2][4];
    #pragma unroll
    for (int rg = 0; rg < 2; ++rg)
        #pragma unroll
        for (int f = 0; f < 4; ++f)
            xv[rg][f] = *(const short4v*)(xzp +
                ((((size_t)(rgg0 + rg) * TCHUNK + 0) * 16 + wc) * 4 + f) * 256 +
                lane * 4);

    int cur = 0;
    for (int tl = 0; tl < steps; ++tl) {
        const int t = t0 + tl;

        // acc init from prefetched xz
        f32x4 acc[2][4];
        #pragma unroll
        for (int rg = 0; rg < 2; ++rg)
            #pragma unroll
            for (int f = 0; f < 4; ++f)
                #pragma unroll
                for (int rr = 0; rr < 4; ++rr)
                    acc[rg][f][rr] = bf2f((unsigned short)xv[rg][f][rr]);

        // prefetch next tl (overlaps MFMA+gates)
        if (tl + 1 < steps) {
            #pragma unroll
            for (int rg = 0; rg < 2; ++rg)
                #pragma unroll
                for (int f = 0; f < 4; ++f)
                    xv[rg][f] = *(const short4v*)(xzp +
                        ((((size_t)(rgg0 + rg) * TCHUNK + tl + 1) * 16 + wc) * 4 + f) * 256 +
                        lane * 4);
        }

        // h @ R : 8 k-steps, B-frag shared across 2 row-groups
        #pragma unroll
        for (int kk = 0; kk < 8; ++kk) {
            short8 a0 = *(const short8*)&h_f[cur][0][kk][lane * 8];
            short8 a1 = *(const short8*)&h_f[cur][1][kk][lane * 8];
            short8 bf[4];
            #pragma unroll
            for (int f = 0; f < 4; ++f)
                bf[f] = *(const short8*)(wrow[f] + kk * 32);
            #pragma unroll
            for (int f = 0; f < 4; ++f) {
                acc[0][f] = __builtin_amdgcn_mfma_f32_16x16x32_bf16(a0, bf[f], acc[0][f], 0, 0, 0);
                acc[1][f] = __builtin_amdgcn_mfma_f32_16x16x32_bf16(a1, bf[f], acc[1][f], 0, 0, 0);
            }
        }

        // gates in registers
        #pragma unroll
        for (int rg = 0; rg < 2; ++rg) {
            #pragma unroll
            for (int rr = 0; rr < 4; ++rr) {
                float zi = acc[rg][0][rr] + bias[0];
                float zf = acc[rg][1][rr] + bias[1];
                float zg = acc[rg][2][rr] + bias[2];
                float zo = acc[rg][3][rr] + bias[3];
                float ig = sigf(zi), fg = sigf(zf);
                float gg = tanhfast(zg), og = sigf(zo);
                float cc = fg * creg[rg][rr] + ig * gg;
                float hh = og * tanhfast(cc);
                creg[rg][rr] = cc;
                const short hb = f2bf(hh);
                // write new h into other buffer (no read-hazard: dbuf)
                h_f[cur ^ 1][rg][kkw][(law + p * 4 + rr) * 8 + jw] = hb;
                const int row = r0 + rg * 16 + p * 4 + rr;
                if (t == len_r[rg][rr] - 1)
                    xlast[(size_t)row * E_DIM + e] = hh;
                if (tl == steps - 1) {
                    h_state[(size_t)row * E_DIM + e] = hb;
                    c_state[(size_t)row * E_DIM + e] = cc;
                }
            }
        }
        cur ^= 1;
        __syncthreads();   // new h visible before next step's a-reads
    }
}

// ---------------------------------------------------------------------------
// Head MLP + L2 normalize (unchanged).
// ---------------------------------------------------------------------------
__global__ __launch_bounds__(256) void k_head(
    const float* __restrict__ xlast,
    const float* __restrict__ W0, const float* __restrict__ b0,
    const float* __restrict__ W1, const float* __restrict__ b1,
    float* __restrict__ out)
{
    const int n = blockIdx.x;
    const int j = threadIdx.x;

    __shared__ __align__(16) float xsh[E_DIM];
    __shared__ __align__(16) float y0[E_DIM];
    __shared__ float part[4];

    xsh[j] = xlast[(size_t)n * E_DIM + j];
    __syncthreads();

    float acc = b0[j];
    for (int k4 = 0; k4 < E_DIM; k4 += 4) {
        float4 xv = *reinterpret_cast<const float4*>(&xsh[k4]);
        #pragma unroll
        for (int kk = 0; kk < 4; ++kk)
            acc += (&xv.x)[kk] * W0[(size_t)(k4 + kk) * E_DIM + j];
    }
    y0[j] = fmaxf(acc, 0.f);
    __syncthreads();

    acc = b1[j];
    for (int k4 = 0; k4 < E_DIM; k4 += 4) {
        float4 yv = *reinterpret_cast<const float4*>(&y0[k4]);
        #pragma unroll
        for (int kk = 0; kk < 4; ++kk)
            acc += (&yv.x)[kk] * W1[(size_t)(k4 + kk) * E_DIM + j];
    }

    float sq = acc * acc;
    #pragma unroll
    for (int off = 32; off > 0; off >>= 1)
        sq += __shfl_xor(sq, off, 64);
    if ((j & 63) == 0) part[j >> 6] = sq;
    __syncthreads();
    float total = part[0] + part[1] + part[2] + part[3];

    out[(size_t)n * E_DIM + j] = acc * rsqrtf(total);
}

// ---------------------------------------------------------------------------
extern "C" void kernel_launch(void* const* d_in, const int* in_sizes, int n_in,
                              void* d_out, int out_size, void* d_ws, size_t ws_size,
                              hipStream_t stream) {
    const int*   code   = (const int*)  d_in[0];
    const float* aux    = (const float*)d_in[1];
    const int*   length = (const int*)  d_in[2];
    // d_in[3] = is_training (ignored)
    const float* W_lin  = (const float*)d_in[4];
    const float* b_lin  = (const float*)d_in[5];
    const float* K      = (const float*)d_in[6];
    const float* R      = (const float*)d_in[7];
    const float* b      = (const float*)d_in[8];
    const float* W0     = (const float*)d_in[9];
    const float* b0     = (const float*)d_in[10];
    const float* W1     = (const float*)d_in[11];
    const float* b1     = (const float*)d_in[12];
    float* out = (float*)d_out;

    // workspace layout (bytes, 16B aligned); total ~48.5 MB
    char* ws = (char*)d_ws;
    short* Wt      = (short*)(ws + 0);            //  1,048,576
    short* Wlt     = (short*)(ws + 1048576);      //    278,528
    float* xlast   = (float*)(ws + 1327104);      //  2,097,152
    short* h_state = (short*)(ws + 3424256);      //  1,048,576
    float* c_state = (float*)(ws + 4472832);      //  2,097,152
    short* xzp     = (short*)(ws + 6569984);      // 41,943,040

    k_prepwl<<<68,  256, 0, stream>>>(W_lin, Wlt);
    k_prep  <<<128, 256, 0, stream>>>(K, R, Wt);

    for (int c = 0; c < T_STEPS / TCHUNK; ++c) {
        const int t0 = c * TCHUNK;
        k_fused<<<64 * TCHUNK, 512, 0, stream>>>(
            code, aux, Wlt, b_lin, Wt, xzp, t0);
        k_rec<<<N_BATCH / BMR, 1024, 0, stream>>>(xzp, length, Wt, b,
                                                  h_state, c_state, xlast, t0);
    }

    k_head<<<N_BATCH, 256, 0, stream>>>(xlast, W0, b0, W1, b1, out);
}

// Round 7
// 816.304 us; speedup vs baseline: 1.7828x; 1.7828x over previous
//
#include <hip/hip_runtime.h>
#include <hip/hip_bf16.h>
#include <math.h>

#define N_BATCH 2048
#define T_STEPS 50
#define NCODES  40
#define MH      526
#define AUXD    10
#define WLROWS  536    // MH + AUXD
#define E_DIM   256
#define G_DIM   1024   // 4*E
#define BM      16     // batch rows per recurrence block
#define TCHUNK  10     // time steps per chunk (5 chunks)
#define MBLK    32     // (n,t) rows per fused block

typedef __attribute__((ext_vector_type(8))) short short8;   // 8 bf16 = 4 VGPR
typedef __attribute__((ext_vector_type(4))) short short4v;  // 4 bf16 = 2 VGPR
typedef __attribute__((ext_vector_type(4))) float f32x4;

__device__ __forceinline__ short f2bf(float f) {
    __hip_bfloat16 h = __float2bfloat16(f);
    return *reinterpret_cast<short*>(&h);
}
__device__ __forceinline__ float bf2f(unsigned short u) {
    return __uint_as_float(((unsigned int)u) << 16);
}
__device__ __forceinline__ float sigf(float x) {
    return 1.f / (1.f + __expf(-x));
}
__device__ __forceinline__ float tanhfast(float x) {
    return 2.f / (1.f + __expf(-2.f * x)) - 1.f;
}

// ---------------------------------------------------------------------------
// Weight preps: pre-permute into exact per-wave consumption order so every
// wave B-load is one contiguous 1 KB block.
// Frag-group layout: dst[(fg*64 + lane)*8 + j], lane=p*16+lr.
// ---------------------------------------------------------------------------
// Wrec (R-half for k_rec): fg = (kk*8 + (eb*4+g))*8 + w
//   content = R[kk*32+p*8+j][g*256 + w*32 + eb*16 + lr]
__global__ __launch_bounds__(256) void k_prep_wrec(
    const float* __restrict__ R, short* __restrict__ Wrec)
{
    const int gid  = blockIdx.x * 256 + threadIdx.x;   // 32768
    const int fg   = gid >> 6, lane = gid & 63;
    const int p    = lane >> 4, lr = lane & 15;
    const int kk   = fg >> 6;
    const int j8   = (fg >> 3) & 7;
    const int w    = fg & 7;
    const int eb   = j8 >> 2, g = j8 & 3;
    const int n    = g * 256 + w * 32 + eb * 16 + lr;
    short* dst = Wrec + (size_t)fg * 512 + lane * 8;
    #pragma unroll
    for (int j = 0; j < 8; ++j)
        dst[j] = f2bf(R[(size_t)(kk * 32 + p * 8 + j) * G_DIM + n]);
}

// WfK (K for k_fused phase 3): fg = (kb*8 + cb)*8 + w
//   content = K[kb*32+p*8+j][w*128 + cb*16 + lr]
__global__ __launch_bounds__(256) void k_prep_wfk(
    const float* __restrict__ K, short* __restrict__ WfK)
{
    const int gid  = blockIdx.x * 256 + threadIdx.x;   // 32768
    const int fg   = gid >> 6, lane = gid & 63;
    const int p    = lane >> 4, lr = lane & 15;
    const int kb   = fg >> 6;
    const int cb   = (fg >> 3) & 7;
    const int w    = fg & 7;
    const int n    = w * 128 + cb * 16 + lr;
    short* dst = WfK + (size_t)fg * 512 + lane * 8;
    #pragma unroll
    for (int j = 0; j < 8; ++j)
        dst[j] = f2bf(K[(size_t)(kb * 32 + p * 8 + j) * G_DIM + n]);
}

// WfL (W_lin for k_fused phase 2): fg = (kk*2 + cb)*8 + w, kk 0..16
//   content = W_lin[kk*32+p*8+j][w*32 + cb*16 + lr], 0 beyond row 535
__global__ __launch_bounds__(256) void k_prep_wfl(
    const float* __restrict__ W_lin, short* __restrict__ WfL)
{
    const int gid  = blockIdx.x * 256 + threadIdx.x;   // 17408
    const int fg   = gid >> 6, lane = gid & 63;
    const int p    = lane >> 4, lr = lane & 15;
    const int kk   = fg >> 4;
    const int cb   = (fg >> 3) & 1;
    const int w    = fg & 7;
    const int n    = w * 32 + cb * 16 + lr;
    short* dst = WfL + (size_t)fg * 512 + lane * 8;
    #pragma unroll
    for (int j = 0; j < 8; ++j) {
        const int k = kk * 32 + p * 8 + j;
        dst[j] = (k < WLROWS) ? f2bf(W_lin[(size_t)k * E_DIM + n]) : (short)0;
    }
}

// ---------------------------------------------------------------------------
// Fused embed + xz GEMM, tl-major. Block = 32 consecutive n at fixed tl.
// Output in k_rec fragment order: frag idx = (rgg*TCHUNK+tl)*64 + wc*8 + j8,
// 256 shorts each, lane writes short4 at +lane*4.
// Producer (w,cb) -> consumer: wc=(w&1)*4+(cb>>1), j8=(cb&1)*4+(w>>1).
// ---------------------------------------------------------------------------
__global__ __launch_bounds__(512) void k_fused(
    const int* __restrict__ code, const float* __restrict__ aux,
    const short* __restrict__ WfL, const float* __restrict__ b_lin,
    const short* __restrict__ WfK, short* __restrict__ xzp, int t0)
{
    const int tid  = threadIdx.x;
    const int w    = tid >> 6;
    const int lane = tid & 63;
    const int lr   = lane & 15;
    const int p    = lane >> 4;
    const int tl   = blockIdx.x >> 6;          // 0..TCHUNK-1
    const int ng   = blockIdx.x & 63;
    const int n0   = ng * MBLK;                // 32 consecutive batch rows
    const int t    = t0 + tl;

    __shared__ __align__(16) short oh[MBLK][552];
    __shared__ __align__(16) short xs[MBLK][264];

    // ---- zero one-hot ----
    for (int i = tid; i < (MBLK * 552) / 8; i += 512)
        ((int4*)&oh[0][0])[i] = (int4){0, 0, 0, 0};
    __syncthreads();

    // ---- scatter codes (presence; duplicates idempotent; drop c==0) ----
    for (int i = tid; i < MBLK * NCODES; i += 512) {
        const int r = i / NCODES;
        const int j = i - r * NCODES;
        const int c = code[((size_t)(n0 + r) * T_STEPS + t) * NCODES + j];
        if (c > 0) ((unsigned short*)&oh[0][0])[r * 552 + (c - 1)] = 0x3F80;
    }
    if (tid < MBLK * AUXD) {
        const int r = tid / AUXD;
        const int a = tid - r * AUXD;
        oh[r][MH + a] = f2bf(aux[((size_t)(n0 + r) * T_STEPS + t) * AUXD + a]);
    }
    __syncthreads();

    const short* wfl_thr = WfL + (size_t)w * 512 + lane * 8;
    const short* wfk_thr = WfK + (size_t)w * 512 + lane * 8;

    // ---- Phase 2: xs = relu(oh @ WfL^T + b_lin), wave cols w*32.. ----
    {
        f32x4 acc[2][2];
        #pragma unroll
        for (int rb = 0; rb < 2; ++rb)
            #pragma unroll
            for (int cb = 0; cb < 2; ++cb)
                acc[rb][cb] = (f32x4){0.f, 0.f, 0.f, 0.f};

        for (int kk = 0; kk < 17; ++kk) {
            short8 a0 = *(const short8*)&oh[lr][kk * 32 + p * 8];
            short8 a1 = *(const short8*)&oh[16 + lr][kk * 32 + p * 8];
            #pragma unroll
            for (int cb = 0; cb < 2; ++cb) {
                short8 bf = *(const short8*)(wfl_thr + (size_t)(kk * 2 + cb) * 4096);
                acc[0][cb] = __builtin_amdgcn_mfma_f32_16x16x32_bf16(a0, bf, acc[0][cb], 0, 0, 0);
                acc[1][cb] = __builtin_amdgcn_mfma_f32_16x16x32_bf16(a1, bf, acc[1][cb], 0, 0, 0);
            }
        }
        float bias[2];
        #pragma unroll
        for (int cb = 0; cb < 2; ++cb) bias[cb] = b_lin[w * 32 + cb * 16 + lr];
        __syncthreads();
        #pragma unroll
        for (int rb = 0; rb < 2; ++rb)
            #pragma unroll
            for (int cb = 0; cb < 2; ++cb)
                #pragma unroll
                for (int rr = 0; rr < 4; ++rr)
                    xs[rb * 16 + p * 4 + rr][w * 32 + cb * 16 + lr] =
                        f2bf(fmaxf(acc[rb][cb][rr] + bias[cb], 0.f));
        __syncthreads();
    }

    // ---- Phase 3: xz = xs @ WfK^T, frag-order output ----
    {
        f32x4 acc[2][8];
        #pragma unroll
        for (int rb = 0; rb < 2; ++rb)
            #pragma unroll
            for (int cb = 0; cb < 8; ++cb)
                acc[rb][cb] = (f32x4){0.f, 0.f, 0.f, 0.f};

        for (int kb = 0; kb < 8; ++kb) {
            short8 a0 = *(const short8*)&xs[lr][kb * 32 + p * 8];
            short8 a1 = *(const short8*)&xs[16 + lr][kb * 32 + p * 8];
            short8 bf[8];
            #pragma unroll
            for (int cb = 0; cb < 8; ++cb)
                bf[cb] = *(const short8*)(wfk_thr + (size_t)(kb * 8 + cb) * 4096);
            #pragma unroll
            for (int cb = 0; cb < 8; ++cb) {
                acc[0][cb] = __builtin_amdgcn_mfma_f32_16x16x32_bf16(a0, bf[cb], acc[0][cb], 0, 0, 0);
                acc[1][cb] = __builtin_amdgcn_mfma_f32_16x16x32_bf16(a1, bf[cb], acc[1][cb], 0, 0, 0);
            }
        }
        #pragma unroll
        for (int rb = 0; rb < 2; ++rb) {
            const int rgg = ng * 2 + rb;     // 16-row group = k_rec block id
            #pragma unroll
            for (int cb = 0; cb < 8; ++cb) {
                const int wc = (w & 1) * 4 + (cb >> 1);
                const int j8 = (cb & 1) * 4 + (w >> 1);
                short4v v;
                #pragma unroll
                for (int rr = 0; rr < 4; ++rr) v[rr] = f2bf(acc[rb][cb][rr]);
                *(short4v*)(xzp +
                    (((size_t)rgg * TCHUNK + tl) * 64 + wc * 8 + j8) * 256 +
                    lane * 4) = v;
            }
        }
    }
}

// ---------------------------------------------------------------------------
// Recurrence v4: 128 blocks x 512 thr (8 waves), BM=16. Wave w owns e-cols
// w*32+eb*16+lr for all 4 gates (8 acc frags). Weights streamed from Wrec in
// exact consumption order (contiguous 1KB per wave-load), double-buffered.
// h in frag-major dbuf LDS (1 barrier/step). xz coalesced + prefetched.
// ---------------------------------------------------------------------------
__global__ __launch_bounds__(512, 2) void k_rec(
    const short* __restrict__ xzp, const int* __restrict__ length,
    const short* __restrict__ Wrec, const float* __restrict__ b,
    short* __restrict__ h_state, float* __restrict__ c_state,
    float* __restrict__ xlast, int t0)
{
    const int tid  = threadIdx.x;
    const int w    = tid >> 6;
    const int lane = tid & 63;
    const int lr   = lane & 15;
    const int p    = lane >> 4;
    const int r0   = blockIdx.x * BM;
    const int rgg  = blockIdx.x;

    __shared__ __align__(16) short h_f[2][8][512]; // [buf][kk][lane*8+j], 16KB
    __shared__ int s_len[BM];
    __shared__ int s_maxlen;

    if (tid < BM) s_len[tid] = length[r0 + tid];
    __syncthreads();
    if (tid == 0) {
        int m = 0;
        for (int r2 = 0; r2 < BM; ++r2) m = max(m, s_len[r2]);
        s_maxlen = m;
    }
    __syncthreads();
    const int mlen = s_maxlen;
    if (mlen <= t0) return;
    const int steps = min(TCHUNK, mlen - t0);

    int len_r[4];
    #pragma unroll
    for (int rr = 0; rr < 4; ++rr) len_r[rr] = s_len[p * 4 + rr];

    float bias[8];
    #pragma unroll
    for (int eb = 0; eb < 2; ++eb)
        #pragma unroll
        for (int g = 0; g < 4; ++g)
            bias[eb * 4 + g] = b[g * 256 + w * 32 + eb * 16 + lr];

    // h_f write offsets for this thread's two e-columns
    int hoff[2];
    #pragma unroll
    for (int eb = 0; eb < 2; ++eb)
        hoff[eb] = ((eb * 2 + (lr >> 3)) * 16) * 8 + (lr & 7);

    float creg[8];
    if (t0 == 0) {
        for (int i = tid; i < 4096; i += 512) ((int*)h_f)[i] = 0;  // buf 0
        #pragma unroll
        for (int i = 0; i < 8; ++i) creg[i] = 0.f;
    } else {
        #pragma unroll
        for (int eb = 0; eb < 2; ++eb)
            #pragma unroll
            for (int rr = 0; rr < 4; ++rr) {
                const int row = r0 + p * 4 + rr;
                const int e   = w * 32 + eb * 16 + lr;
                creg[eb * 4 + rr] = c_state[(size_t)row * E_DIM + e];
                h_f[0][w][hoff[eb] + (p * 4 + rr) * 8] =
                    h_state[(size_t)row * E_DIM + e];
            }
    }
    __syncthreads();

    const short* wthr = Wrec + (size_t)w * 512 + lane * 8;
    const short* xzb  = xzp + ((size_t)rgg * TCHUNK) * 64 * 256 +
                        (size_t)(w * 8) * 256 + lane * 4;

    // prefetch xz for tl=0
    short4v xv[8];
    #pragma unroll
    for (int j8 = 0; j8 < 8; ++j8)
        xv[j8] = *(const short4v*)(xzb + j8 * 256);

    int cur = 0;
    for (int tl = 0; tl < steps; ++tl) {
        const int t = t0 + tl;

        // acc init from prefetched xz
        f32x4 acc[8];
        #pragma unroll
        for (int j8 = 0; j8 < 8; ++j8)
            #pragma unroll
            for (int rr = 0; rr < 4; ++rr)
                acc[j8][rr] = bf2f((unsigned short)xv[j8][rr]);

        // prefetch next tl (longest latency -> issue first)
        if (tl + 1 < steps) {
            #pragma unroll
            for (int j8 = 0; j8 < 8; ++j8)
                xv[j8] = *(const short4v*)(xzb + (size_t)(tl + 1) * 64 * 256 + j8 * 256);
        }

        // a-frags from LDS
        short8 a[8];
        #pragma unroll
        for (int kk = 0; kk < 8; ++kk)
            a[kk] = *(const short8*)&h_f[cur][kk][lane * 8];

        // h @ R with double-buffered contiguous B loads
        short8 bA[8], bB[8];
        #pragma unroll
        for (int j8 = 0; j8 < 8; ++j8)
            bA[j8] = *(const short8*)(wthr + (size_t)j8 * 4096);
        #pragma unroll
        for (int kp = 0; kp < 4; ++kp) {
            const int k_e = kp * 2, k_o = kp * 2 + 1;
            #pragma unroll
            for (int j8 = 0; j8 < 8; ++j8)
                bB[j8] = *(const short8*)(wthr + (size_t)(k_o * 8 + j8) * 4096);
            #pragma unroll
            for (int j8 = 0; j8 < 8; ++j8)
                acc[j8] = __builtin_amdgcn_mfma_f32_16x16x32_bf16(
                    a[k_e], bA[j8], acc[j8], 0, 0, 0);
            if (kp < 3) {
                #pragma unroll
                for (int j8 = 0; j8 < 8; ++j8)
                    bA[j8] = *(const short8*)(wthr + (size_t)((k_e + 2) * 8 + j8) * 4096);
            }
            #pragma unroll
            for (int j8 = 0; j8 < 8; ++j8)
                acc[j8] = __builtin_amdgcn_mfma_f32_16x16x32_bf16(
                    a[k_o], bB[j8], acc[j8], 0, 0, 0);
        }

        // gates in registers
        short* hw = &h_f[cur ^ 1][w][0];
        #pragma unroll
        for (int eb = 0; eb < 2; ++eb) {
            #pragma unroll
            for (int rr = 0; rr < 4; ++rr) {
                float zi = acc[eb * 4 + 0][rr] + bias[eb * 4 + 0];
                float zf = acc[eb * 4 + 1][rr] + bias[eb * 4 + 1];
                float zg = acc[eb * 4 + 2][rr] + bias[eb * 4 + 2];
                float zo = acc[eb * 4 + 3][rr] + bias[eb * 4 + 3];
                float ig = sigf(zi), fg = sigf(zf);
                float gg = tanhfast(zg), og = sigf(zo);
                float cc = fg * creg[eb * 4 + rr] + ig * gg;
                float hh = og * tanhfast(cc);
                creg[eb * 4 + rr] = cc;
                const short hb = f2bf(hh);
                hw[hoff[eb] + (p * 4 + rr) * 8] = hb;
                const int row = r0 + p * 4 + rr;
                const int e   = w * 32 + eb * 16 + lr;
                if (t == len_r[rr] - 1)
                    xlast[(size_t)row * E_DIM + e] = hh;
                if (tl == steps - 1) {
                    h_state[(size_t)row * E_DIM + e] = hb;
                    c_state[(size_t)row * E_DIM + e] = cc;
                }
            }
        }
        cur ^= 1;
        __syncthreads();   // new h visible before next step's a-reads
    }
}

// ---------------------------------------------------------------------------
// Head MLP + L2 normalize (unchanged).
// ---------------------------------------------------------------------------
__global__ __launch_bounds__(256) void k_head(
    const float* __restrict__ xlast,
    const float* __restrict__ W0, const float* __restrict__ b0,
    const float* __restrict__ W1, const float* __restrict__ b1,
    float* __restrict__ out)
{
    const int n = blockIdx.x;
    const int j = threadIdx.x;

    __shared__ __align__(16) float xsh[E_DIM];
    __shared__ __align__(16) float y0[E_DIM];
    __shared__ float part[4];

    xsh[j] = xlast[(size_t)n * E_DIM + j];
    __syncthreads();

    float acc = b0[j];
    for (int k4 = 0; k4 < E_DIM; k4 += 4) {
        float4 xv = *reinterpret_cast<const float4*>(&xsh[k4]);
        #pragma unroll
        for (int kk = 0; kk < 4; ++kk)
            acc += (&xv.x)[kk] * W0[(size_t)(k4 + kk) * E_DIM + j];
    }
    y0[j] = fmaxf(acc, 0.f);
    __syncthreads();

    acc = b1[j];
    for (int k4 = 0; k4 < E_DIM; k4 += 4) {
        float4 yv = *reinterpret_cast<const float4*>(&y0[k4]);
        #pragma unroll
        for (int kk = 0; kk < 4; ++kk)
            acc += (&yv.x)[kk] * W1[(size_t)(k4 + kk) * E_DIM + j];
    }

    float sq = acc * acc;
    #pragma unroll
    for (int off = 32; off > 0; off >>= 1)
        sq += __shfl_xor(sq, off, 64);
    if ((j & 63) == 0) part[j >> 6] = sq;
    __syncthreads();
    float total = part[0] + part[1] + part[2] + part[3];

    out[(size_t)n * E_DIM + j] = acc * rsqrtf(total);
}

// ---------------------------------------------------------------------------
extern "C" void kernel_launch(void* const* d_in, const int* in_sizes, int n_in,
                              void* d_out, int out_size, void* d_ws, size_t ws_size,
                              hipStream_t stream) {
    const int*   code   = (const int*)  d_in[0];
    const float* aux    = (const float*)d_in[1];
    const int*   length = (const int*)  d_in[2];
    // d_in[3] = is_training (ignored)
    const float* W_lin  = (const float*)d_in[4];
    const float* b_lin  = (const float*)d_in[5];
    const float* K      = (const float*)d_in[6];
    const float* R      = (const float*)d_in[7];
    const float* b      = (const float*)d_in[8];
    const float* W0     = (const float*)d_in[9];
    const float* b0     = (const float*)d_in[10];
    const float* W1     = (const float*)d_in[11];
    const float* b1     = (const float*)d_in[12];
    float* out = (float*)d_out;

    // workspace layout (bytes, 16B aligned); total ~48.5 MB
    char* ws = (char*)d_ws;
    short* Wrec    = (short*)(ws + 0);            //    524,288
    short* WfK     = (short*)(ws + 524288);       //    524,288
    short* WfL     = (short*)(ws + 1048576);      //    278,528
    float* xlast   = (float*)(ws + 1327104);      //  2,097,152
    short* h_state = (short*)(ws + 3424256);      //  1,048,576
    float* c_state = (float*)(ws + 4472832);      //  2,097,152
    short* xzp     = (short*)(ws + 6569984);      // 41,943,040

    k_prep_wrec<<<128, 256, 0, stream>>>(R, Wrec);
    k_prep_wfk <<<128, 256, 0, stream>>>(K, WfK);
    k_prep_wfl <<<68,  256, 0, stream>>>(W_lin, WfL);

    for (int c = 0; c < T_STEPS / TCHUNK; ++c) {
        const int t0 = c * TCHUNK;
        k_fused<<<64 * TCHUNK, 512, 0, stream>>>(
            code, aux, WfL, b_lin, WfK, xzp, t0);
        k_rec<<<N_BATCH / BM, 512, 0, stream>>>(xzp, length, Wrec, b,
                                                h_state, c_state, xlast, t0);
    }

    k_head<<<N_BATCH, 256, 0, stream>>>(xlast, W0, b0, W1, b1, out);
}